// Round 1
// baseline (1109.251 us; speedup 1.0000x reference)
//
#include <hip/hip_runtime.h>

// ---------- types ----------
typedef __bf16  bf16x8 __attribute__((ext_vector_type(8)));
typedef float   f32x4  __attribute__((ext_vector_type(4)));
typedef _Float16 f16x2 __attribute__((ext_vector_type(2)));

// ---------- helpers ----------
__device__ __forceinline__ float bf2f(unsigned short u) {
    unsigned int x = ((unsigned int)u) << 16;
    return __builtin_bit_cast(float, x);
}
__device__ __forceinline__ unsigned short f2bf(float f) {
    // round-to-nearest-even; inputs here are small integers / +-1 so exact
    unsigned int u = __builtin_bit_cast(unsigned int, f);
    u += 0x7fffu + ((u >> 16) & 1u);
    return (unsigned short)(u >> 16);
}
__device__ __forceinline__ void async_cp16(const void* g, void* l) {
    __builtin_amdgcn_global_load_lds(
        (const __attribute__((address_space(1))) void*)g,
        (__attribute__((address_space(3))) void*)l, 16, 0, 0);
}

// ---------- GEMM: C[M,N] = sum_k A[M,K]*B[N,K], integer codes in bf16 ----------
// epilogue: v = acc * (wscale[0] * rowinv[row]) + bias[col]; optional exact GELU.
template <bool GELU, typename OutT>
__global__ __launch_bounds__(256) void gemm_bt(
    const unsigned short* __restrict__ A,   // M x K bf16 (integer-valued)
    const unsigned short* __restrict__ B,   // N x K bf16 (ternary)
    const float* __restrict__ rowinv,       // per-row dequant (absmax/127)
    const float* __restrict__ wscale,       // &scale_w
    const float* __restrict__ bias,         // N
    OutT* __restrict__ C,                   // M x N
    int M, int N, int K)
{
    __shared__ unsigned short sA[128 * 64];
    __shared__ unsigned short sB[128 * 64];

    const int tid  = threadIdx.x;
    const int lane = tid & 63;
    const int wid  = tid >> 6;
    const int lm   = lane & 15;
    const int quad = lane >> 4;
    const int wr   = (wid >> 1) * 64;   // wave row origin in tile
    const int wc   = (wid & 1) * 64;    // wave col origin in tile

    const long long rowA0 = (long long)blockIdx.y * 128;
    const long long rowB0 = (long long)blockIdx.x * 128;

    // staging: thread t handles row (tid>>3)+32*r, 16B chunk (tid&7) of the 128B row
    const unsigned short* aP = A + (rowA0 + (tid >> 3)) * (long long)K + (tid & 7) * 8;
    const unsigned short* bP = B + (rowB0 + (tid >> 3)) * (long long)K + (tid & 7) * 8;
    unsigned short* sA_t = &sA[tid * 8];
    unsigned short* sB_t = &sB[tid * 8];
    const long long rstep = 32LL * K;

    f32x4 acc[4][4] = {};

    for (int k0 = 0; k0 < K; k0 += 64) {
#pragma unroll
        for (int r = 0; r < 4; ++r) {
            async_cp16(aP + r * rstep + k0, sA_t + r * 2048);
            async_cp16(bP + r * rstep + k0, sB_t + r * 2048);
        }
        __syncthreads();   // drains vmcnt (global_load_lds) + barrier
#pragma unroll
        for (int kk = 0; kk < 64; kk += 32) {
            bf16x8 af[4], bfr[4];
#pragma unroll
            for (int i = 0; i < 4; ++i)
                af[i] = *(const bf16x8*)&sA[(wr + i * 16 + lm) * 64 + kk + quad * 8];
#pragma unroll
            for (int j = 0; j < 4; ++j)
                bfr[j] = *(const bf16x8*)&sB[(wc + j * 16 + lm) * 64 + kk + quad * 8];
#pragma unroll
            for (int i = 0; i < 4; ++i)
#pragma unroll
                for (int j = 0; j < 4; ++j)
                    acc[i][j] = __builtin_amdgcn_mfma_f32_16x16x32_bf16(
                        af[i], bfr[j], acc[i][j], 0, 0, 0);
        }
        __syncthreads();
    }

    const float sw = wscale[0];
    float bj[4];
#pragma unroll
    for (int j = 0; j < 4; ++j)
        bj[j] = bias[rowB0 + wc + j * 16 + lm];

    // C/D layout (measured m89/m91): col = lane&15, row = quad*4 + reg
#pragma unroll
    for (int i = 0; i < 4; ++i) {
#pragma unroll
        for (int r = 0; r < 4; ++r) {
            const long long gr = rowA0 + wr + i * 16 + quad * 4 + r;
            const float rs = sw * rowinv[gr];
#pragma unroll
            for (int j = 0; j < 4; ++j) {
                const long long gc = rowB0 + wc + j * 16 + lm;
                float v = acc[i][j][r] * rs + bj[j];
                if constexpr (GELU)
                    v = 0.5f * v * (1.0f + erff(v * 0.70710678118654752f));
                C[gr * (long long)N + gc] = (OutT)v;
            }
        }
    }
}

// ---------- LN + absmax int8 fake-quant over x (d=2048, fp32 in, bf16 codes out) ----------
__global__ __launch_bounds__(256) void ln_quant_x(
    const float* __restrict__ x, unsigned short* __restrict__ xq,
    float* __restrict__ xinv)
{
    const int t = blockIdx.x;
    const int tid = threadIdx.x;
    const int lane = tid & 63, wid = tid >> 6;
    const float4* row = (const float4*)(x + (long long)t * 2048);
    float4 v0 = row[tid];
    float4 v1 = row[tid + 256];
    float vv[8] = {v0.x, v0.y, v0.z, v0.w, v1.x, v1.y, v1.z, v1.w};

    float s = 0.f, mn = vv[0], mx = vv[0];
#pragma unroll
    for (int i = 0; i < 8; ++i) { s += vv[i]; mn = fminf(mn, vv[i]); mx = fmaxf(mx, vv[i]); }
#pragma unroll
    for (int off = 32; off > 0; off >>= 1) {
        s += __shfl_down(s, off);
        mn = fminf(mn, __shfl_down(mn, off));
        mx = fmaxf(mx, __shfl_down(mx, off));
    }
    __shared__ float rS[4], rMn[4], rMx[4];
    if (lane == 0) { rS[wid] = s; rMn[wid] = mn; rMx[wid] = mx; }
    __syncthreads();
    s  = rS[0] + rS[1] + rS[2] + rS[3];
    mn = fminf(fminf(rMn[0], rMn[1]), fminf(rMn[2], rMn[3]));
    mx = fmaxf(fmaxf(rMx[0], rMx[1]), fmaxf(rMx[2], rMx[3]));
    const float mu = s * (1.0f / 2048.0f);

    float ssc = 0.f;
#pragma unroll
    for (int i = 0; i < 8; ++i) { float d = vv[i] - mu; ssc += d * d; }
#pragma unroll
    for (int off = 32; off > 0; off >>= 1) ssc += __shfl_down(ssc, off);
    __syncthreads();
    if (lane == 0) rS[wid] = ssc;
    __syncthreads();
    ssc = rS[0] + rS[1] + rS[2] + rS[3];

    const float var  = ssc * (1.0f / 2048.0f);
    const float rstd = 1.0f / sqrtf(var + 1e-5f);
    float am = fmaxf(mx - mu, mu - mn) * rstd;   // exact absmax of xn (monotone)
    am = fmaxf(am, 1e-5f);
    const float scale = 127.0f / am;

    unsigned short q[8];
#pragma unroll
    for (int i = 0; i < 8; ++i) {
        float xn = (vv[i] - mu) * rstd;
        float qf = fminf(fmaxf(rintf(xn * scale), -128.0f), 127.0f);
        q[i] = f2bf(qf);
    }
    ushort4* orow = (ushort4*)(xq + (long long)t * 2048);
    ushort4 o0 = {q[0], q[1], q[2], q[3]};
    ushort4 o1 = {q[4], q[5], q[6], q[7]};
    orow[tid] = o0;
    orow[tid + 256] = o1;
    if (tid == 0) xinv[t] = am / 127.0f;
}

// ---------- LN + quant over h rows (d=8192, fp16 in, bf16 codes out, in-place) ----------
__global__ __launch_bounds__(256) void ln_quant_h(
    unsigned short* __restrict__ h, float* __restrict__ hinv)
{
    const long long t = blockIdx.x;
    const int tid = threadIdx.x;
    const int lane = tid & 63, wid = tid >> 6;
    unsigned short* row = h + t * 8192;

    uint4 raw[4];
    float v[32];
#pragma unroll
    for (int c = 0; c < 4; ++c) raw[c] = ((const uint4*)row)[c * 256 + tid];
#pragma unroll
    for (int c = 0; c < 4; ++c) {
        unsigned int u[4] = {raw[c].x, raw[c].y, raw[c].z, raw[c].w};
#pragma unroll
        for (int k = 0; k < 4; ++k) {
            f16x2 p = __builtin_bit_cast(f16x2, u[k]);
            v[c * 8 + k * 2 + 0] = (float)p[0];
            v[c * 8 + k * 2 + 1] = (float)p[1];
        }
    }

    float s = 0.f, mn = v[0], mx = v[0];
#pragma unroll
    for (int i = 0; i < 32; ++i) { s += v[i]; mn = fminf(mn, v[i]); mx = fmaxf(mx, v[i]); }
#pragma unroll
    for (int off = 32; off > 0; off >>= 1) {
        s += __shfl_down(s, off);
        mn = fminf(mn, __shfl_down(mn, off));
        mx = fmaxf(mx, __shfl_down(mx, off));
    }
    __shared__ float rS[4], rMn[4], rMx[4];
    if (lane == 0) { rS[wid] = s; rMn[wid] = mn; rMx[wid] = mx; }
    __syncthreads();
    s  = rS[0] + rS[1] + rS[2] + rS[3];
    mn = fminf(fminf(rMn[0], rMn[1]), fminf(rMn[2], rMn[3]));
    mx = fmaxf(fmaxf(rMx[0], rMx[1]), fmaxf(rMx[2], rMx[3]));
    const float mu = s * (1.0f / 8192.0f);

    float ssc = 0.f;
#pragma unroll
    for (int i = 0; i < 32; ++i) { float d = v[i] - mu; ssc += d * d; }
#pragma unroll
    for (int off = 32; off > 0; off >>= 1) ssc += __shfl_down(ssc, off);
    __syncthreads();
    if (lane == 0) rS[wid] = ssc;
    __syncthreads();
    ssc = rS[0] + rS[1] + rS[2] + rS[3];

    const float var  = ssc * (1.0f / 8192.0f);
    const float rstd = 1.0f / sqrtf(var + 1e-5f);
    float am = fmaxf(mx - mu, mu - mn) * rstd;
    am = fmaxf(am, 1e-5f);
    const float scale = 127.0f / am;

#pragma unroll
    for (int c = 0; c < 4; ++c) {
        unsigned int w[4];
#pragma unroll
        for (int k = 0; k < 4; ++k) {
            float xn0 = (v[c * 8 + k * 2 + 0] - mu) * rstd;
            float xn1 = (v[c * 8 + k * 2 + 1] - mu) * rstd;
            unsigned short q0 = f2bf(fminf(fmaxf(rintf(xn0 * scale), -128.0f), 127.0f));
            unsigned short q1 = f2bf(fminf(fmaxf(rintf(xn1 * scale), -128.0f), 127.0f));
            w[k] = (unsigned int)q0 | ((unsigned int)q1 << 16);
        }
        uint4 o = {w[0], w[1], w[2], w[3]};
        ((uint4*)row)[c * 256 + tid] = o;
    }
    if (tid == 0) hinv[t] = am / 127.0f;
}

// ---------- deterministic |w| reduction (stage 1) ----------
__global__ __launch_bounds__(256) void reduce_abs(
    const float4* __restrict__ w4, int n4, float* __restrict__ partial)
{
    const int tid = threadIdx.x;
    const int lane = tid & 63, wid = tid >> 6;
    float s = 0.f;
    for (int i = blockIdx.x * 256 + tid; i < n4; i += gridDim.x * 256) {
        float4 v = w4[i];
        s += fabsf(v.x) + fabsf(v.y) + fabsf(v.z) + fabsf(v.w);
    }
#pragma unroll
    for (int off = 32; off > 0; off >>= 1) s += __shfl_down(s, off);
    __shared__ float rS[4];
    if (lane == 0) rS[wid] = s;
    __syncthreads();
    if (tid == 0) partial[blockIdx.x] = rS[0] + rS[1] + rS[2] + rS[3];
}

// ---------- stage 2: scales for both weights ----------
__global__ __launch_bounds__(256) void finalize_scales(
    const float* __restrict__ p1, const float* __restrict__ p2,
    float* __restrict__ scales)
{
    const int tid = threadIdx.x;
    const int lane = tid & 63, wid = tid >> 6;
    float s1 = 0.f, s2 = 0.f;
    for (int i = tid; i < 1024; i += 256) { s1 += p1[i]; s2 += p2[i]; }
#pragma unroll
    for (int off = 32; off > 0; off >>= 1) {
        s1 += __shfl_down(s1, off);
        s2 += __shfl_down(s2, off);
    }
    __shared__ float rA[4], rB[4];
    if (lane == 0) { rA[wid] = s1; rB[wid] = s2; }
    __syncthreads();
    if (tid == 0) {
        float m1 = fmaxf((rA[0] + rA[1] + rA[2] + rA[3]) * (1.0f / 16777216.0f), 1e-8f);
        float m2 = fmaxf((rB[0] + rB[1] + rB[2] + rB[3]) * (1.0f / 16777216.0f), 1e-8f);
        scales[0] = m1;
        scales[1] = m2;
    }
}

// ---------- ternary weight quant: bf16 codes in {-1,0,+1} ----------
__global__ __launch_bounds__(256) void quant_w(
    const float4* __restrict__ w4, unsigned short* __restrict__ wq,
    const float* __restrict__ scales, int sidx, int n4)
{
    const float s = scales[sidx];
    for (int i = blockIdx.x * 256 + threadIdx.x; i < n4; i += gridDim.x * 256) {
        float4 v = w4[i];
        ushort4 o;
        o.x = f2bf(fminf(fmaxf(rintf(v.x / s), -1.0f), 1.0f));
        o.y = f2bf(fminf(fmaxf(rintf(v.y / s), -1.0f), 1.0f));
        o.z = f2bf(fminf(fmaxf(rintf(v.z / s), -1.0f), 1.0f));
        o.w = f2bf(fminf(fmaxf(rintf(v.w / s), -1.0f), 1.0f));
        ((ushort4*)wq)[i] = o;
    }
}

// ---------- launch ----------
extern "C" void kernel_launch(void* const* d_in, const int* in_sizes, int n_in,
                              void* d_out, int out_size, void* d_ws, size_t ws_size,
                              hipStream_t stream)
{
    const float* x  = (const float*)d_in[0];   // 8192 x 2048
    const float* w1 = (const float*)d_in[1];   // 8192 x 2048
    const float* b1 = (const float*)d_in[2];   // 8192
    const float* w2 = (const float*)d_in[3];   // 2048 x 8192
    const float* b2 = (const float*)d_in[4];   // 2048
    float* out = (float*)d_out;                // 8192 x 2048

    char* ws = (char*)d_ws;
    const size_t SZ_WQ = 33554432;   // 8192*2048*2
    unsigned short* w1q = (unsigned short*)(ws);
    unsigned short* w2q = (unsigned short*)(ws + SZ_WQ);
    unsigned short* xq  = (unsigned short*)(ws + 2 * SZ_WQ);
    unsigned short* h   = (unsigned short*)(ws + 3 * SZ_WQ);       // 8192*8192*2 = 128MB
    float* xinv   = (float*)(ws + 3 * SZ_WQ + 134217728);
    float* hinv   = xinv + 8192;
    float* part1  = hinv + 8192;
    float* part2  = part1 + 1024;
    float* scales = part2 + 1024;

    const int N4W = 4194304;  // 16.7M / 4

    reduce_abs<<<1024, 256, 0, stream>>>((const float4*)w1, N4W, part1);
    reduce_abs<<<1024, 256, 0, stream>>>((const float4*)w2, N4W, part2);
    finalize_scales<<<1, 256, 0, stream>>>(part1, part2, scales);
    quant_w<<<4096, 256, 0, stream>>>((const float4*)w1, w1q, scales, 0, N4W);
    quant_w<<<4096, 256, 0, stream>>>((const float4*)w2, w2q, scales, 1, N4W);
    ln_quant_x<<<8192, 256, 0, stream>>>(x, xq, xinv);

    // h = gelu(xq @ w1q^T * (sw1*xinv) + b1), stored fp16
    gemm_bt<true, _Float16><<<dim3(64, 64), 256, 0, stream>>>(
        xq, w1q, xinv, &scales[0], b1, (_Float16*)h, 8192, 8192, 2048);

    ln_quant_h<<<8192, 256, 0, stream>>>(h, hinv);

    // out = hq @ w2q^T * (sw2*hinv) + b2, fp32
    gemm_bt<false, float><<<dim3(16, 64), 256, 0, stream>>>(
        h, w2q, hinv, &scales[1], b2, out, 8192, 2048, 8192);
}

// Round 2
// 895.196 us; speedup vs baseline: 1.2391x; 1.2391x over previous
//
#include <hip/hip_runtime.h>

// ---------- types ----------
typedef __bf16  bf16x8 __attribute__((ext_vector_type(8)));
typedef float   f32x4  __attribute__((ext_vector_type(4)));
typedef _Float16 f16x2 __attribute__((ext_vector_type(2)));

// ---------- helpers ----------
__device__ __forceinline__ unsigned short f2bf(float f) {
    // round-to-nearest-even; inputs here are small integers / +-1 so exact
    unsigned int u = __builtin_bit_cast(unsigned int, f);
    u += 0x7fffu + ((u >> 16) & 1u);
    return (unsigned short)(u >> 16);
}
__device__ __forceinline__ void async_cp16(const void* g, void* l) {
    __builtin_amdgcn_global_load_lds(
        (const __attribute__((address_space(1))) void*)g,
        (__attribute__((address_space(3))) void*)l, 16, 0, 0);
}

// ---------- GEMM: C[M,N] = sum_k A[M,K]*B[N,K], integer codes in bf16 ----------
// LDS layout XOR-swizzled: row r, chunk c (16B) lives at slot c^(r&7).
// global_load_lds dst is fixed (base+lane*16), so the swizzle is applied to the
// SOURCE chunk each staging thread fetches. Reads then hit 8 distinct bank
// groups x 2 lanes (2-way = free, m136) instead of 16-way conflicts.
template <bool GELU, typename OutT>
__global__ __launch_bounds__(256) void gemm_bt(
    const unsigned short* __restrict__ A,   // M x K bf16 (integer-valued)
    const unsigned short* __restrict__ B,   // N x K bf16 (ternary)
    const float* __restrict__ rowinv,       // per-row dequant (absmax/127)
    const float* __restrict__ wscale,       // &scale_w
    const float* __restrict__ bias,         // N
    OutT* __restrict__ C,                   // M x N
    int M, int N, int K)
{
    __shared__ unsigned short sA[128 * 64];
    __shared__ unsigned short sB[128 * 64];

    const int tid  = threadIdx.x;
    const int lane = tid & 63;
    const int wid  = tid >> 6;
    const int lm   = lane & 15;
    const int quad = lane >> 4;
    const int wr   = (wid >> 1) * 64;   // wave row origin in tile
    const int wc   = (wid & 1) * 64;    // wave col origin in tile

    const long long rowA0 = (long long)blockIdx.y * 128;
    const long long rowB0 = (long long)blockIdx.x * 128;

    // staging: thread t owns LDS slot (tid&7) of row (tid>>3)+32*r; it fetches
    // the XOR-swizzled source chunk. (row&7) is invariant under +32*r.
    const int srow   = tid >> 3;
    const int slot   = tid & 7;
    const int gchunk = slot ^ (srow & 7);

    const unsigned short* aP = A + (rowA0 + srow) * (long long)K + gchunk * 8;
    const unsigned short* bP = B + (rowB0 + srow) * (long long)K + gchunk * 8;
    unsigned short* sA_t = &sA[tid * 8];
    unsigned short* sB_t = &sB[tid * 8];
    const long long rstep = 32LL * K;

    f32x4 acc[4][4] = {};

    const int swz = lm & 7;   // read-side swizzle key: (row & 7) == (lm & 7)

    for (int k0 = 0; k0 < K; k0 += 64) {
#pragma unroll
        for (int r = 0; r < 4; ++r) {
            async_cp16(aP + r * rstep + k0, sA_t + r * 2048);
            async_cp16(bP + r * rstep + k0, sB_t + r * 2048);
        }
        __syncthreads();   // drains vmcnt (global_load_lds) + barrier
#pragma unroll
        for (int kk8 = 0; kk8 < 8; kk8 += 4) {     // kk8 = (k within tile)/8
            const int coff = ((kk8 + quad) ^ swz) * 8;   // swizzled chunk offset (shorts)
            bf16x8 af[4], bfr[4];
#pragma unroll
            for (int i = 0; i < 4; ++i)
                af[i] = *(const bf16x8*)&sA[(wr + i * 16 + lm) * 64 + coff];
#pragma unroll
            for (int j = 0; j < 4; ++j)
                bfr[j] = *(const bf16x8*)&sB[(wc + j * 16 + lm) * 64 + coff];
#pragma unroll
            for (int i = 0; i < 4; ++i)
#pragma unroll
                for (int j = 0; j < 4; ++j)
                    acc[i][j] = __builtin_amdgcn_mfma_f32_16x16x32_bf16(
                        af[i], bfr[j], acc[i][j], 0, 0, 0);
        }
        __syncthreads();
    }

    const float sw = wscale[0];
    float bj[4];
#pragma unroll
    for (int j = 0; j < 4; ++j)
        bj[j] = bias[rowB0 + wc + j * 16 + lm];

    // C/D layout (measured m89/m91): col = lane&15, row = quad*4 + reg
#pragma unroll
    for (int i = 0; i < 4; ++i) {
#pragma unroll
        for (int r = 0; r < 4; ++r) {
            const long long gr = rowA0 + wr + i * 16 + quad * 4 + r;
            const float rs = sw * rowinv[gr];
#pragma unroll
            for (int j = 0; j < 4; ++j) {
                const long long gc = rowB0 + wc + j * 16 + lm;
                float v = acc[i][j][r] * rs + bj[j];
                if constexpr (GELU)
                    v = 0.5f * v * (1.0f + erff(v * 0.70710678118654752f));
                C[gr * (long long)N + gc] = (OutT)v;
            }
        }
    }
}

// ---------- LN + absmax int8 fake-quant over x (d=2048, fp32 in, bf16 codes out) ----------
__global__ __launch_bounds__(256) void ln_quant_x(
    const float* __restrict__ x, unsigned short* __restrict__ xq,
    float* __restrict__ xinv)
{
    const int t = blockIdx.x;
    const int tid = threadIdx.x;
    const int lane = tid & 63, wid = tid >> 6;
    const float4* row = (const float4*)(x + (long long)t * 2048);
    float4 v0 = row[tid];
    float4 v1 = row[tid + 256];
    float vv[8] = {v0.x, v0.y, v0.z, v0.w, v1.x, v1.y, v1.z, v1.w};

    float s = 0.f, mn = vv[0], mx = vv[0];
#pragma unroll
    for (int i = 0; i < 8; ++i) { s += vv[i]; mn = fminf(mn, vv[i]); mx = fmaxf(mx, vv[i]); }
#pragma unroll
    for (int off = 32; off > 0; off >>= 1) {
        s += __shfl_down(s, off);
        mn = fminf(mn, __shfl_down(mn, off));
        mx = fmaxf(mx, __shfl_down(mx, off));
    }
    __shared__ float rS[4], rMn[4], rMx[4];
    if (lane == 0) { rS[wid] = s; rMn[wid] = mn; rMx[wid] = mx; }
    __syncthreads();
    s  = rS[0] + rS[1] + rS[2] + rS[3];
    mn = fminf(fminf(rMn[0], rMn[1]), fminf(rMn[2], rMn[3]));
    mx = fmaxf(fmaxf(rMx[0], rMx[1]), fmaxf(rMx[2], rMx[3]));
    const float mu = s * (1.0f / 2048.0f);

    float ssc = 0.f;
#pragma unroll
    for (int i = 0; i < 8; ++i) { float d = vv[i] - mu; ssc += d * d; }
#pragma unroll
    for (int off = 32; off > 0; off >>= 1) ssc += __shfl_down(ssc, off);
    __syncthreads();
    if (lane == 0) rS[wid] = ssc;
    __syncthreads();
    ssc = rS[0] + rS[1] + rS[2] + rS[3];

    const float var  = ssc * (1.0f / 2048.0f);
    const float rstd = 1.0f / sqrtf(var + 1e-5f);
    float am = fmaxf(mx - mu, mu - mn) * rstd;   // exact absmax of xn (monotone)
    am = fmaxf(am, 1e-5f);
    const float scale = 127.0f / am;

    unsigned short q[8];
#pragma unroll
    for (int i = 0; i < 8; ++i) {
        float xn = (vv[i] - mu) * rstd;
        float qf = fminf(fmaxf(rintf(xn * scale), -128.0f), 127.0f);
        q[i] = f2bf(qf);
    }
    ushort4* orow = (ushort4*)(xq + (long long)t * 2048);
    ushort4 o0 = {q[0], q[1], q[2], q[3]};
    ushort4 o1 = {q[4], q[5], q[6], q[7]};
    orow[tid] = o0;
    orow[tid + 256] = o1;
    if (tid == 0) xinv[t] = am / 127.0f;
}

// ---------- LN + quant over h rows (d=8192, fp16 in, bf16 codes out, in-place) ----------
__global__ __launch_bounds__(256) void ln_quant_h(
    unsigned short* __restrict__ h, float* __restrict__ hinv)
{
    const long long t = blockIdx.x;
    const int tid = threadIdx.x;
    const int lane = tid & 63, wid = tid >> 6;
    unsigned short* row = h + t * 8192;

    uint4 raw[4];
    float v[32];
#pragma unroll
    for (int c = 0; c < 4; ++c) raw[c] = ((const uint4*)row)[c * 256 + tid];
#pragma unroll
    for (int c = 0; c < 4; ++c) {
        unsigned int u[4] = {raw[c].x, raw[c].y, raw[c].z, raw[c].w};
#pragma unroll
        for (int k = 0; k < 4; ++k) {
            f16x2 p = __builtin_bit_cast(f16x2, u[k]);
            v[c * 8 + k * 2 + 0] = (float)p[0];
            v[c * 8 + k * 2 + 1] = (float)p[1];
        }
    }

    float s = 0.f, mn = v[0], mx = v[0];
#pragma unroll
    for (int i = 0; i < 32; ++i) { s += v[i]; mn = fminf(mn, v[i]); mx = fmaxf(mx, v[i]); }
#pragma unroll
    for (int off = 32; off > 0; off >>= 1) {
        s += __shfl_down(s, off);
        mn = fminf(mn, __shfl_down(mn, off));
        mx = fmaxf(mx, __shfl_down(mx, off));
    }
    __shared__ float rS[4], rMn[4], rMx[4];
    if (lane == 0) { rS[wid] = s; rMn[wid] = mn; rMx[wid] = mx; }
    __syncthreads();
    s  = rS[0] + rS[1] + rS[2] + rS[3];
    mn = fminf(fminf(rMn[0], rMn[1]), fminf(rMn[2], rMn[3]));
    mx = fmaxf(fmaxf(rMx[0], rMx[1]), fmaxf(rMx[2], rMx[3]));
    const float mu = s * (1.0f / 8192.0f);

    float ssc = 0.f;
#pragma unroll
    for (int i = 0; i < 32; ++i) { float d = v[i] - mu; ssc += d * d; }
#pragma unroll
    for (int off = 32; off > 0; off >>= 1) ssc += __shfl_down(ssc, off);
    __syncthreads();
    if (lane == 0) rS[wid] = ssc;
    __syncthreads();
    ssc = rS[0] + rS[1] + rS[2] + rS[3];

    const float var  = ssc * (1.0f / 8192.0f);
    const float rstd = 1.0f / sqrtf(var + 1e-5f);
    float am = fmaxf(mx - mu, mu - mn) * rstd;
    am = fmaxf(am, 1e-5f);
    const float scale = 127.0f / am;

#pragma unroll
    for (int c = 0; c < 4; ++c) {
        unsigned int w[4];
#pragma unroll
        for (int k = 0; k < 4; ++k) {
            float xn0 = (v[c * 8 + k * 2 + 0] - mu) * rstd;
            float xn1 = (v[c * 8 + k * 2 + 1] - mu) * rstd;
            unsigned short q0 = f2bf(fminf(fmaxf(rintf(xn0 * scale), -128.0f), 127.0f));
            unsigned short q1 = f2bf(fminf(fmaxf(rintf(xn1 * scale), -128.0f), 127.0f));
            w[k] = (unsigned int)q0 | ((unsigned int)q1 << 16);
        }
        uint4 o = {w[0], w[1], w[2], w[3]};
        ((uint4*)row)[c * 256 + tid] = o;
    }
    if (tid == 0) hinv[t] = am / 127.0f;
}

// ---------- deterministic |w| reduction (stage 1) ----------
__global__ __launch_bounds__(256) void reduce_abs(
    const float4* __restrict__ w4, int n4, float* __restrict__ partial)
{
    const int tid = threadIdx.x;
    const int lane = tid & 63, wid = tid >> 6;
    float s = 0.f;
    for (int i = blockIdx.x * 256 + tid; i < n4; i += gridDim.x * 256) {
        float4 v = w4[i];
        s += fabsf(v.x) + fabsf(v.y) + fabsf(v.z) + fabsf(v.w);
    }
#pragma unroll
    for (int off = 32; off > 0; off >>= 1) s += __shfl_down(s, off);
    __shared__ float rS[4];
    if (lane == 0) rS[wid] = s;
    __syncthreads();
    if (tid == 0) partial[blockIdx.x] = rS[0] + rS[1] + rS[2] + rS[3];
}

// ---------- stage 2: scales for both weights ----------
__global__ __launch_bounds__(256) void finalize_scales(
    const float* __restrict__ p1, const float* __restrict__ p2,
    float* __restrict__ scales)
{
    const int tid = threadIdx.x;
    const int lane = tid & 63, wid = tid >> 6;
    float s1 = 0.f, s2 = 0.f;
    for (int i = tid; i < 1024; i += 256) { s1 += p1[i]; s2 += p2[i]; }
#pragma unroll
    for (int off = 32; off > 0; off >>= 1) {
        s1 += __shfl_down(s1, off);
        s2 += __shfl_down(s2, off);
    }
    __shared__ float rA[4], rB[4];
    if (lane == 0) { rA[wid] = s1; rB[wid] = s2; }
    __syncthreads();
    if (tid == 0) {
        float m1 = fmaxf((rA[0] + rA[1] + rA[2] + rA[3]) * (1.0f / 16777216.0f), 1e-8f);
        float m2 = fmaxf((rB[0] + rB[1] + rB[2] + rB[3]) * (1.0f / 16777216.0f), 1e-8f);
        scales[0] = m1;
        scales[1] = m2;
    }
}

// ---------- ternary weight quant: bf16 codes in {-1,0,+1} ----------
__global__ __launch_bounds__(256) void quant_w(
    const float4* __restrict__ w4, unsigned short* __restrict__ wq,
    const float* __restrict__ scales, int sidx, int n4)
{
    const float s = scales[sidx];
    for (int i = blockIdx.x * 256 + threadIdx.x; i < n4; i += gridDim.x * 256) {
        float4 v = w4[i];
        ushort4 o;
        o.x = f2bf(fminf(fmaxf(rintf(v.x / s), -1.0f), 1.0f));
        o.y = f2bf(fminf(fmaxf(rintf(v.y / s), -1.0f), 1.0f));
        o.z = f2bf(fminf(fmaxf(rintf(v.z / s), -1.0f), 1.0f));
        o.w = f2bf(fminf(fmaxf(rintf(v.w / s), -1.0f), 1.0f));
        ((ushort4*)wq)[i] = o;
    }
}

// ---------- launch ----------
extern "C" void kernel_launch(void* const* d_in, const int* in_sizes, int n_in,
                              void* d_out, int out_size, void* d_ws, size_t ws_size,
                              hipStream_t stream)
{
    const float* x  = (const float*)d_in[0];   // 8192 x 2048
    const float* w1 = (const float*)d_in[1];   // 8192 x 2048
    const float* b1 = (const float*)d_in[2];   // 8192
    const float* w2 = (const float*)d_in[3];   // 2048 x 8192
    const float* b2 = (const float*)d_in[4];   // 2048
    float* out = (float*)d_out;                // 8192 x 2048

    char* ws = (char*)d_ws;
    const size_t SZ_WQ = 33554432;   // 8192*2048*2
    unsigned short* w1q = (unsigned short*)(ws);
    unsigned short* w2q = (unsigned short*)(ws + SZ_WQ);
    unsigned short* xq  = (unsigned short*)(ws + 2 * SZ_WQ);
    unsigned short* h   = (unsigned short*)(ws + 3 * SZ_WQ);       // 8192*8192*2 = 128MB
    float* xinv   = (float*)(ws + 3 * SZ_WQ + 134217728);
    float* hinv   = xinv + 8192;
    float* part1  = hinv + 8192;
    float* part2  = part1 + 1024;
    float* scales = part2 + 1024;

    const int N4W = 4194304;  // 16.7M / 4

    reduce_abs<<<1024, 256, 0, stream>>>((const float4*)w1, N4W, part1);
    reduce_abs<<<1024, 256, 0, stream>>>((const float4*)w2, N4W, part2);
    finalize_scales<<<1, 256, 0, stream>>>(part1, part2, scales);
    quant_w<<<4096, 256, 0, stream>>>((const float4*)w1, w1q, scales, 0, N4W);
    quant_w<<<4096, 256, 0, stream>>>((const float4*)w2, w2q, scales, 1, N4W);
    ln_quant_x<<<8192, 256, 0, stream>>>(x, xq, xinv);

    // h = gelu(xq @ w1q^T * (sw1*xinv) + b1), stored fp16
    gemm_bt<true, _Float16><<<dim3(64, 64), 256, 0, stream>>>(
        xq, w1q, xinv, &scales[0], b1, (_Float16*)h, 8192, 8192, 2048);

    ln_quant_h<<<8192, 256, 0, stream>>>(h, hinv);

    // out = hq @ w2q^T * (sw2*hinv) + b2, fp32
    gemm_bt<false, float><<<dim3(16, 64), 256, 0, stream>>>(
        h, w2q, hinv, &scales[1], b2, out, 8192, 2048, 8192);
}

// Round 4
// 629.700 us; speedup vs baseline: 1.7616x; 1.4216x over previous
//
#include <hip/hip_runtime.h>

// ---------- types ----------
typedef int     i32x4 __attribute__((ext_vector_type(4)));
typedef _Float16 f16x2 __attribute__((ext_vector_type(2)));

// ---------- helpers ----------
__device__ __forceinline__ void async_cp16(const void* g, void* l) {
    __builtin_amdgcn_global_load_lds(
        (const __attribute__((address_space(1))) void*)g,
        (__attribute__((address_space(3))) void*)l, 16, 0, 0);
}

// ---------- GEMM: C[M,N] = sum_k A[M,K]*B[N,K], int8 codes, i32 MFMA ----------
// Tile 128x128, BK=128 (bytes). LDS row stride = 128 B = exactly 32 banks, so
// the same XOR swizzle as the bf16 version applies: row r, 16B chunk c lives at
// slot c^(r&7); staging threads fetch the permuted SOURCE chunk (global_load_lds
// dst is wave-uniform base + lane*16 and cannot scatter). Fragment reads then
// hit 8 distinct bank groups x 2 lanes = 2-way = free (m136).
// NOTE on fragment k-order: A and B tiles are built identically, so any
// consistent k-permutation in the HW fragment map cancels in the dot product —
// only A/B INCONSISTENCY can break correctness (R3 bug was in ln_quant_x).
template <bool GELU, typename OutT>
__global__ __launch_bounds__(256) void gemm_i8(
    const signed char* __restrict__ A,   // M x K int8 codes
    const signed char* __restrict__ B,   // N x K int8 ternary
    const float* __restrict__ rowinv,    // per-row dequant (absmax/127)
    const float* __restrict__ wscale,    // &scale_w
    const float* __restrict__ bias,      // N
    OutT* __restrict__ C,                // M x N
    int M, int N, int K)
{
    __shared__ signed char sA[128 * 128];
    __shared__ signed char sB[128 * 128];

    const int tid  = threadIdx.x;
    const int lane = tid & 63;
    const int wid  = tid >> 6;
    const int lm   = lane & 15;
    const int quad = lane >> 4;
    const int wr   = (wid >> 1) * 64;   // wave row origin in tile
    const int wc   = (wid & 1) * 64;    // wave col origin in tile

    const long long rowA0 = (long long)blockIdx.y * 128;
    const long long rowB0 = (long long)blockIdx.x * 128;

    // staging: thread t owns LDS slot (tid&7) of row (tid>>3)+32*r
    const int srow   = tid >> 3;
    const int slot   = tid & 7;
    const int gchunk = slot ^ (srow & 7);

    const signed char* aP = A + (rowA0 + srow) * (long long)K + gchunk * 16;
    const signed char* bP = B + (rowB0 + srow) * (long long)K + gchunk * 16;
    signed char* sA_t = &sA[tid * 16];
    signed char* sB_t = &sB[tid * 16];
    const long long rstep = 32LL * K;

    i32x4 acc[4][4] = {};

    const int swz = lm & 7;   // read-side swizzle key: (row & 7) == (lm & 7)

    for (int k0 = 0; k0 < K; k0 += 128) {
#pragma unroll
        for (int r = 0; r < 4; ++r) {
            async_cp16(aP + r * rstep + k0, sA_t + r * 4096);
            async_cp16(bP + r * rstep + k0, sB_t + r * 4096);
        }
        __syncthreads();   // drains vmcnt (global_load_lds) + barrier
#pragma unroll
        for (int ks = 0; ks < 2; ++ks) {          // two K=64 MFMA steps
            const int coff = ((ks * 4 + quad) ^ swz) * 16;   // swizzled 16B chunk
            i32x4 af[4], bfr[4];
#pragma unroll
            for (int i = 0; i < 4; ++i)
                af[i] = *(const i32x4*)&sA[(wr + i * 16 + lm) * 128 + coff];
#pragma unroll
            for (int j = 0; j < 4; ++j)
                bfr[j] = *(const i32x4*)&sB[(wc + j * 16 + lm) * 128 + coff];
#pragma unroll
            for (int i = 0; i < 4; ++i)
#pragma unroll
                for (int j = 0; j < 4; ++j)
                    acc[i][j] = __builtin_amdgcn_mfma_i32_16x16x64_i8(
                        af[i], bfr[j], acc[i][j], 0, 0, 0);
        }
        __syncthreads();
    }

    const float sw = wscale[0];
    float bj[4];
#pragma unroll
    for (int j = 0; j < 4; ++j)
        bj[j] = bias[rowB0 + wc + j * 16 + lm];

    // C/D layout (m89/m91, dtype-independent m121-128): col=lane&15, row=quad*4+reg
#pragma unroll
    for (int i = 0; i < 4; ++i) {
#pragma unroll
        for (int r = 0; r < 4; ++r) {
            const long long gr = rowA0 + wr + i * 16 + quad * 4 + r;
            const float rs = sw * rowinv[gr];
#pragma unroll
            for (int j = 0; j < 4; ++j) {
                const long long gc = rowB0 + wc + j * 16 + lm;
                float v = (float)acc[i][j][r] * rs + bj[j];
                if constexpr (GELU)
                    v = 0.5f * v * (1.0f + erff(v * 0.70710678118654752f));
                C[gr * (long long)N + gc] = (OutT)v;
            }
        }
    }
}

// ---------- LN + absmax int8 fake-quant over x (d=2048, fp32 in, int8 out) ----------
// Column-order-preserving stores: thread t holds cols {4t..4t+3} and
// {1024+4t..1024+4t+3}; they MUST land at those byte offsets (R3 bug: a single
// int2 store at 8t scrambled xq's columns vs w1q's natural order).
__global__ __launch_bounds__(256) void ln_quant_x(
    const float* __restrict__ x, signed char* __restrict__ xq,
    float* __restrict__ xinv)
{
    const int t = blockIdx.x;
    const int tid = threadIdx.x;
    const int lane = tid & 63, wid = tid >> 6;
    const float4* row = (const float4*)(x + (long long)t * 2048);
    float4 v0 = row[tid];
    float4 v1 = row[tid + 256];
    float vv[8] = {v0.x, v0.y, v0.z, v0.w, v1.x, v1.y, v1.z, v1.w};

    float s = 0.f, mn = vv[0], mx = vv[0];
#pragma unroll
    for (int i = 0; i < 8; ++i) { s += vv[i]; mn = fminf(mn, vv[i]); mx = fmaxf(mx, vv[i]); }
#pragma unroll
    for (int off = 32; off > 0; off >>= 1) {
        s += __shfl_down(s, off);
        mn = fminf(mn, __shfl_down(mn, off));
        mx = fmaxf(mx, __shfl_down(mx, off));
    }
    __shared__ float rS[4], rMn[4], rMx[4];
    if (lane == 0) { rS[wid] = s; rMn[wid] = mn; rMx[wid] = mx; }
    __syncthreads();
    s  = rS[0] + rS[1] + rS[2] + rS[3];
    mn = fminf(fminf(rMn[0], rMn[1]), fminf(rMn[2], rMn[3]));
    mx = fmaxf(fmaxf(rMx[0], rMx[1]), fmaxf(rMx[2], rMx[3]));
    const float mu = s * (1.0f / 2048.0f);

    float ssc = 0.f;
#pragma unroll
    for (int i = 0; i < 8; ++i) { float d = vv[i] - mu; ssc += d * d; }
#pragma unroll
    for (int off = 32; off > 0; off >>= 1) ssc += __shfl_down(ssc, off);
    __syncthreads();
    if (lane == 0) rS[wid] = ssc;
    __syncthreads();
    ssc = rS[0] + rS[1] + rS[2] + rS[3];

    const float var  = ssc * (1.0f / 2048.0f);
    const float rstd = 1.0f / sqrtf(var + 1e-5f);
    float am = fmaxf(mx - mu, mu - mn) * rstd;   // exact absmax of xn (monotone)
    am = fmaxf(am, 1e-5f);
    const float scale = 127.0f / am;

    unsigned int b0 = 0, b1 = 0;
#pragma unroll
    for (int i = 0; i < 8; ++i) {
        float xn = (vv[i] - mu) * rstd;
        int qi = (int)fminf(fmaxf(rintf(xn * scale), -128.0f), 127.0f);
        unsigned int byte = (unsigned int)(qi & 0xff);
        if (i < 4) b0 |= byte << (i * 8);
        else       b1 |= byte << ((i - 4) * 8);
    }
    int* orow = (int*)(xq + (long long)t * 2048);
    orow[tid]       = (int)b0;   // cols 4t..4t+3
    orow[tid + 256] = (int)b1;   // cols 1024+4t..1024+4t+3
    if (tid == 0) xinv[t] = am / 127.0f;
}

// ---------- LN + quant over h rows (d=8192, fp16 in, int8 out) ----------
__global__ __launch_bounds__(256) void ln_quant_h(
    const unsigned short* __restrict__ h, signed char* __restrict__ hq,
    float* __restrict__ hinv)
{
    const long long t = blockIdx.x;
    const int tid = threadIdx.x;
    const int lane = tid & 63, wid = tid >> 6;
    const unsigned short* row = h + t * 8192;

    uint4 raw[4];
    float v[32];
#pragma unroll
    for (int c = 0; c < 4; ++c) raw[c] = ((const uint4*)row)[c * 256 + tid];
#pragma unroll
    for (int c = 0; c < 4; ++c) {
        unsigned int u[4] = {raw[c].x, raw[c].y, raw[c].z, raw[c].w};
#pragma unroll
        for (int k = 0; k < 4; ++k) {
            f16x2 p = __builtin_bit_cast(f16x2, u[k]);
            v[c * 8 + k * 2 + 0] = (float)p[0];
            v[c * 8 + k * 2 + 1] = (float)p[1];
        }
    }

    float s = 0.f, mn = v[0], mx = v[0];
#pragma unroll
    for (int i = 0; i < 32; ++i) { s += v[i]; mn = fminf(mn, v[i]); mx = fmaxf(mx, v[i]); }
#pragma unroll
    for (int off = 32; off > 0; off >>= 1) {
        s += __shfl_down(s, off);
        mn = fminf(mn, __shfl_down(mn, off));
        mx = fmaxf(mx, __shfl_down(mx, off));
    }
    __shared__ float rS[4], rMn[4], rMx[4];
    if (lane == 0) { rS[wid] = s; rMn[wid] = mn; rMx[wid] = mx; }
    __syncthreads();
    s  = rS[0] + rS[1] + rS[2] + rS[3];
    mn = fminf(fminf(rMn[0], rMn[1]), fminf(rMn[2], rMn[3]));
    mx = fmaxf(fmaxf(rMx[0], rMx[1]), fmaxf(rMx[2], rMx[3]));
    const float mu = s * (1.0f / 8192.0f);

    float ssc = 0.f;
#pragma unroll
    for (int i = 0; i < 32; ++i) { float d = v[i] - mu; ssc += d * d; }
#pragma unroll
    for (int off = 32; off > 0; off >>= 1) ssc += __shfl_down(ssc, off);
    __syncthreads();
    if (lane == 0) rS[wid] = ssc;
    __syncthreads();
    ssc = rS[0] + rS[1] + rS[2] + rS[3];

    const float var  = ssc * (1.0f / 8192.0f);
    const float rstd = 1.0f / sqrtf(var + 1e-5f);
    float am = fmaxf(mx - mu, mu - mn) * rstd;
    am = fmaxf(am, 1e-5f);
    const float scale = 127.0f / am;

    // consistent layout: v[c*8+k] is col 2048c+8t+k; int2 at byte 8*(c*256+t) ✓
    signed char* orow = hq + t * 8192;
#pragma unroll
    for (int c = 0; c < 4; ++c) {
        unsigned int b0 = 0, b1 = 0;
#pragma unroll
        for (int k = 0; k < 8; ++k) {
            float xn = (v[c * 8 + k] - mu) * rstd;
            int qi = (int)fminf(fmaxf(rintf(xn * scale), -128.0f), 127.0f);
            unsigned int byte = (unsigned int)(qi & 0xff);
            if (k < 4) b0 |= byte << (k * 8);
            else       b1 |= byte << ((k - 4) * 8);
        }
        int2 o; o.x = (int)b0; o.y = (int)b1;
        ((int2*)orow)[c * 256 + tid] = o;
    }
    if (tid == 0) hinv[t] = am / 127.0f;
}

// ---------- deterministic |w| reduction (stage 1) ----------
__global__ __launch_bounds__(256) void reduce_abs(
    const float4* __restrict__ w4, int n4, float* __restrict__ partial)
{
    const int tid = threadIdx.x;
    const int lane = tid & 63, wid = tid >> 6;
    float s = 0.f;
    for (int i = blockIdx.x * 256 + tid; i < n4; i += gridDim.x * 256) {
        float4 v = w4[i];
        s += fabsf(v.x) + fabsf(v.y) + fabsf(v.z) + fabsf(v.w);
    }
#pragma unroll
    for (int off = 32; off > 0; off >>= 1) s += __shfl_down(s, off);
    __shared__ float rS[4];
    if (lane == 0) rS[wid] = s;
    __syncthreads();
    if (tid == 0) partial[blockIdx.x] = rS[0] + rS[1] + rS[2] + rS[3];
}

// ---------- stage 2: scales for both weights ----------
__global__ __launch_bounds__(256) void finalize_scales(
    const float* __restrict__ p1, const float* __restrict__ p2,
    float* __restrict__ scales)
{
    const int tid = threadIdx.x;
    const int lane = tid & 63, wid = tid >> 6;
    float s1 = 0.f, s2 = 0.f;
    for (int i = tid; i < 1024; i += 256) { s1 += p1[i]; s2 += p2[i]; }
#pragma unroll
    for (int off = 32; off > 0; off >>= 1) {
        s1 += __shfl_down(s1, off);
        s2 += __shfl_down(s2, off);
    }
    __shared__ float rA[4], rB[4];
    if (lane == 0) { rA[wid] = s1; rB[wid] = s2; }
    __syncthreads();
    if (tid == 0) {
        float m1 = fmaxf((rA[0] + rA[1] + rA[2] + rA[3]) * (1.0f / 16777216.0f), 1e-8f);
        float m2 = fmaxf((rB[0] + rB[1] + rB[2] + rB[3]) * (1.0f / 16777216.0f), 1e-8f);
        scales[0] = m1;
        scales[1] = m2;
    }
}

// ---------- ternary weight quant: int8 codes in {-1,0,+1} ----------
__global__ __launch_bounds__(256) void quant_w(
    const float4* __restrict__ w4, signed char* __restrict__ wq,
    const float* __restrict__ scales, int sidx, int n4)
{
    const float s = scales[sidx];
    for (int i = blockIdx.x * 256 + threadIdx.x; i < n4; i += gridDim.x * 256) {
        float4 v = w4[i];
        int q0 = (int)fminf(fmaxf(rintf(v.x / s), -1.0f), 1.0f);
        int q1 = (int)fminf(fmaxf(rintf(v.y / s), -1.0f), 1.0f);
        int q2 = (int)fminf(fmaxf(rintf(v.z / s), -1.0f), 1.0f);
        int q3 = (int)fminf(fmaxf(rintf(v.w / s), -1.0f), 1.0f);
        unsigned int p = (unsigned int)(q0 & 0xff) | ((unsigned int)(q1 & 0xff) << 8)
                       | ((unsigned int)(q2 & 0xff) << 16) | ((unsigned int)(q3 & 0xff) << 24);
        ((unsigned int*)wq)[i] = p;
    }
}

// ---------- launch ----------
extern "C" void kernel_launch(void* const* d_in, const int* in_sizes, int n_in,
                              void* d_out, int out_size, void* d_ws, size_t ws_size,
                              hipStream_t stream)
{
    const float* x  = (const float*)d_in[0];   // 8192 x 2048
    const float* w1 = (const float*)d_in[1];   // 8192 x 2048
    const float* b1 = (const float*)d_in[2];   // 8192
    const float* w2 = (const float*)d_in[3];   // 2048 x 8192
    const float* b2 = (const float*)d_in[4];   // 2048
    float* out = (float*)d_out;                // 8192 x 2048

    char* ws = (char*)d_ws;
    const size_t SZ_WQ = 16777216;             // 8192*2048 int8
    signed char* w1q = (signed char*)(ws);
    signed char* w2q = (signed char*)(ws + SZ_WQ);
    signed char* xq  = (signed char*)(ws + 2 * SZ_WQ);
    unsigned short* h = (unsigned short*)(ws + 3 * SZ_WQ);          // fp16, 128 MB
    signed char* hq  = (signed char*)(ws + 3 * SZ_WQ + 134217728);  // int8, 64 MB
    float* xinv   = (float*)(ws + 3 * SZ_WQ + 134217728 + 67108864);
    float* hinv   = xinv + 8192;
    float* part1  = hinv + 8192;
    float* part2  = part1 + 1024;
    float* scales = part2 + 1024;

    const int N4W = 4194304;  // 16.7M / 4

    reduce_abs<<<1024, 256, 0, stream>>>((const float4*)w1, N4W, part1);
    reduce_abs<<<1024, 256, 0, stream>>>((const float4*)w2, N4W, part2);
    finalize_scales<<<1, 256, 0, stream>>>(part1, part2, scales);
    quant_w<<<4096, 256, 0, stream>>>((const float4*)w1, w1q, scales, 0, N4W);
    quant_w<<<4096, 256, 0, stream>>>((const float4*)w2, w2q, scales, 1, N4W);
    ln_quant_x<<<8192, 256, 0, stream>>>(x, xq, xinv);

    // h = gelu(xq @ w1q^T * (sw1*xinv) + b1), stored fp16
    gemm_i8<true, _Float16><<<dim3(64, 64), 256, 0, stream>>>(
        xq, w1q, xinv, &scales[0], b1, (_Float16*)h, 8192, 8192, 2048);

    ln_quant_h<<<8192, 256, 0, stream>>>(h, hq, hinv);

    // out = hq @ w2q^T * (sw2*hinv) + b2, fp32
    gemm_i8<false, float><<<dim3(16, 64), 256, 0, stream>>>(
        hq, w2q, hinv, &scales[1], b2, out, 8192, 2048, 8192);
}